// Round 10
// baseline (711.775 us; speedup 1.0000x reference)
//
#include <hip/hip_runtime.h>
#include <cstddef>

typedef _Float16 f16x8 __attribute__((ext_vector_type(8)));
typedef _Float16 f16x2 __attribute__((ext_vector_type(2)));
typedef float    f32x4 __attribute__((ext_vector_type(4)));

#define Bc 4096
#define Tc 256
#define NSTEP 257
#define RB 16               // rows per block
#define HSTR 264            // fp16 h-tile row stride (528B)
#define FSTR 260            // f32 hF row stride
#define GSTR 12             // gateC dwords per unit
#define HEAD_OFF 393216     // byte offset of head frags in ws
#define LOG2E 1.4426950408889634f

#if __has_builtin(__builtin_amdgcn_exp2f)
#define EXP2(x) __builtin_amdgcn_exp2f(x)
#else
#define EXP2(x) __builtin_exp2f(x)
#endif

__device__ inline float tanh_(float x) { return 1.f - 2.f * __builtin_amdgcn_rcpf(1.f + __expf(2.f * x)); }

// ---------------------------------------------------------------------------
// Fragment-linear fp16 copies of w_hh (EXP2-PRESCALED) and w_head in ws.
// nc=0 (r), nc=1 (z): scaled by -log2(e); nc=2 (n): scaled by +2*log2(e)
// -> gate phase uses v_exp directly, no per-use scaling muls.
// EVEN/ODD PAIRING: tile (w,p) column c holds unit 32w + 2c + p.
// head frags at HEAD_OFF (unscaled).
// ---------------------------------------------------------------------------
__global__ __launch_bounds__(256) void build_frags(
    const float* __restrict__ w_hh, const float* __restrict__ w_head,
    _Float16* __restrict__ ws)
{
    int flat = blockIdx.x * 256 + threadIdx.x;
    if (blockIdx.x < 96) {
        int f    = flat >> 6;          // 0..383
        int lane = flat & 63;
        int kt   = f & 7;
        int nc   = (f >> 3) % 3;
        int trio = f / 24;
        float scale = (nc == 2) ? 2.f * LOG2E : -LOG2E;
        int c     = nc * 256 + (trio >> 1) * 32 + 2 * (lane & 15) + (trio & 1);
        int kbase = kt * 32 + (lane >> 4) * 8;
        _Float16* dst = ws + (size_t)f * 512 + (size_t)lane * 8;
        #pragma unroll
        for (int j = 0; j < 8; ++j)
            dst[j] = (_Float16)(scale * w_hh[(size_t)(kbase + j) * 768 + c]);
    } else {
        int idx = flat - 96 * 256;     // 0..511
        int kt   = idx >> 6;
        int lane = idx & 63;
        int col   = lane & 15;
        int kbase = kt * 32 + (lane >> 4) * 8;
        _Float16* dst = ws + HEAD_OFF / 2 + (size_t)kt * 512 + (size_t)lane * 8;
        #pragma unroll
        for (int j = 0; j < 8; ++j)
            dst[j] = (col < 2) ? (_Float16)w_head[(size_t)(kbase + j) * 2 + col]
                               : (_Float16)0.f;
    }
}

// ---------------------------------------------------------------------------
// GRU scan: 256 blocks x 512 threads (8 waves), 16 rows per block.
// ONE barrier/step (hA/hB double-buffer, macro-expanded unroll, no lambda).
// exp2-prescaled gates computed in batched stages (4-way ILP on trans pipe).
// 48 B-frags register/AGPR-resident; f32 recurrence state in LDS hF (float2).
// kt=0 MFMA peel from persistent zero-C (no per-step acc zero-init).
// ---------------------------------------------------------------------------
__global__ __attribute__((amdgpu_waves_per_eu(2, 2))) __launch_bounds__(512)
void gru_mfma(
    const float* __restrict__ cond, const float* __restrict__ ivf,
    const float* __restrict__ times,
    const float* __restrict__ w1, const float* __restrict__ b1,
    const float* __restrict__ w2, const float* __restrict__ b2,
    const float* __restrict__ w3, const float* __restrict__ b3,
    const float* __restrict__ wh0, const float* __restrict__ bh0,
    const float* __restrict__ w_ih, const float* __restrict__ b_ih,
    const float* __restrict__ b_hh, const float* __restrict__ b_head,
    const _Float16* __restrict__ wfrag,
    float* __restrict__ out)
{
    __shared__ __align__(16) _Float16 hA[RB * HSTR];      // 8448 B
    __shared__ __align__(16) _Float16 hB[RB * HSTR];      // 8448 B
    __shared__ __align__(8)  float hF[RB * FSTR];         // 16640 B
    __shared__ __align__(16) float xs4[4 * NSTEP * 4];    // 16448 B [q][i][4]
    __shared__ __align__(16) _Float16 headB[4096];        // 8192 B
    __shared__ __align__(16) float gateC[256 * GSTR];     // 12288 B
    __shared__ float  outbuf[2][2][RB][16];               // 4096 B
    __shared__ float  bh2[2];
    __shared__ float  mlp1[RB * 128];
    __shared__ float  mlp2[RB * 128];
    __shared__ float  embS[RB * 64];
    __shared__ float  h0f[RB * 256];

    const int tid  = threadIdx.x;
    const int w    = tid >> 6;
    const int lane = tid & 63;
    const int l15  = lane & 15;
    const int q    = lane >> 4;
    const int row0 = blockIdx.x * RB;

    // ---- preamble: MLP + h0 ----
    for (int o = tid; o < RB * 128; o += 512) {
        int r = o >> 7, c = o & 127;
        float a = b1[c];
        #pragma unroll 4
        for (int k = 0; k < 64; ++k)
            a = fmaf(ivf[(size_t)(row0 + r) * 64 + k], w1[k * 128 + c], a);
        mlp1[o] = fmaxf(a, 0.f);
    }
    __syncthreads();
    for (int o = tid; o < RB * 128; o += 512) {
        int r = o >> 7, c = o & 127;
        float a = b2[c];
        #pragma unroll 4
        for (int k = 0; k < 128; ++k)
            a = fmaf(mlp1[r * 128 + k], w2[k * 128 + c], a);
        mlp2[o] = fmaxf(a, 0.f);
    }
    __syncthreads();
    for (int o = tid; o < RB * 64; o += 512) {
        int r = o >> 6, c = o & 63;
        float a = b3[c];
        #pragma unroll 4
        for (int k = 0; k < 128; ++k)
            a = fmaf(mlp2[r * 128 + k], w3[k * 64 + c], a);
        embS[o] = a;
    }
    __syncthreads();
    for (int o = tid; o < RB * 256; o += 512) {
        int r = o >> 8, c = o & 255;
        float a = bh0[c];
        #pragma unroll 4
        for (int k = 0; k < 128; ++k)
            a = fmaf(cond[(size_t)(row0 + r) * 128 + k], wh0[k * 256 + c], a);
        #pragma unroll 4
        for (int k = 0; k < 64; ++k)
            a = fmaf(embS[r * 64 + k], wh0[(128 + k) * 256 + c], a);
        float h = tanh_(a);
        h0f[o] = h;
        hA[r * HSTR + c] = (_Float16)h;
    }

    for (int o = tid; o < 4 * NSTEP; o += 512) {
        int qg = o / NSTEP, ii = o - qg * NSTEP;
        #pragma unroll
        for (int jj = 0; jj < 4; ++jj) {
            int r = qg * 4 + jj;
            float x = 0.f;
            if (ii >= 1) {
                float a = times[(size_t)(row0 + r) * Tc + (ii - 1)];
                float b = (ii >= 2) ? times[(size_t)(row0 + r) * Tc + (ii - 2)] : 0.f;
                x = a - b;
            }
            xs4[o * 4 + jj] = x;
        }
    }
    {
        const float4* src = (const float4*)(wfrag + HEAD_OFF / 2);
        ((float4*)headB)[tid] = src[tid];
    }
    for (int uu = tid; uu < 256; uu += 512) {
        gateC[uu * GSTR + 0] = -LOG2E * w_ih[uu];
        gateC[uu * GSTR + 1] = -LOG2E * w_ih[256 + uu];
        gateC[uu * GSTR + 2] = 2.f * LOG2E * w_ih[512 + uu];
        gateC[uu * GSTR + 3] = -LOG2E * (b_ih[uu] + b_hh[uu]);
        gateC[uu * GSTR + 4] = -LOG2E * (b_ih[256 + uu] + b_hh[256 + uu]);
        gateC[uu * GSTR + 5] = 2.f * LOG2E * b_ih[512 + uu];
        gateC[uu * GSTR + 6] = 2.f * LOG2E * b_hh[512 + uu];
        gateC[uu * GSTR + 7] = 0.f;
    }
    if (tid < 2) bh2[tid] = b_head[tid];

    // ---- register-resident weight fragments + hF init ----
    const int u0 = w * 32 + 2 * l15;       // even unit
    const int u1 = u0 + 1;                 // odd unit

    f16x8 Bf[2][3][8];
    #pragma unroll
    for (int p = 0; p < 2; ++p)
        #pragma unroll
        for (int nc = 0; nc < 3; ++nc)
            #pragma unroll
            for (int kt = 0; kt < 8; ++kt)
                Bf[p][nc][kt] = *(const f16x8*)(wfrag
                    + (size_t)(((2 * w + p) * 3 + nc) * 8 + kt) * 512
                    + (size_t)lane * 8);

    #pragma unroll
    for (int j = 0; j < 4; ++j) {
        const int m = q * 4 + j;
        *(float2*)(hF + m * FSTR + u0) =
            (float2){h0f[m * 256 + u0], h0f[m * 256 + u1]};
    }

    __syncthreads();

    const f32x4 Z4 = (f32x4){0.f, 0.f, 0.f, 0.f};

// ---- one GRU step (reads HC, writes HN); ONE barrier at end ----
#define GRU_STEP(HC, HN, I, DOHEAD)                                            \
do {                                                                           \
    const int i_ = (I);                                                        \
    if (i_ >= 17 && ((i_ - 17) & 15) == 0) {                                   \
        const int obase = i_ - 17;                                             \
        const int par   = (obase >> 4) & 1;                                    \
        const int e     = tid & 15;                                            \
        const int row   = (tid >> 4) & 15;                                     \
        const int plane = tid >> 8;                                            \
        out[(size_t)plane * ((size_t)Bc * NSTEP)                               \
            + (size_t)(row0 + row) * NSTEP + obase + e]                        \
            = outbuf[par][plane][row][e] + bh2[plane];                         \
    }                                                                          \
    f32x4 aR0, aR1, aZ0, aZ1, aN0, aN1, aH = Z4;                               \
    const _Float16* ab_ = (HC) + l15 * HSTR + q * 8;                           \
    {                                                                          \
        f16x8 Af = *(const f16x8*)(ab_);                                       \
        aR0 = __builtin_amdgcn_mfma_f32_16x16x32_f16(Af, Bf[0][0][0], Z4, 0, 0, 0); \
        aZ0 = __builtin_amdgcn_mfma_f32_16x16x32_f16(Af, Bf[0][1][0], Z4, 0, 0, 0); \
        aN0 = __builtin_amdgcn_mfma_f32_16x16x32_f16(Af, Bf[0][2][0], Z4, 0, 0, 0); \
        aR1 = __builtin_amdgcn_mfma_f32_16x16x32_f16(Af, Bf[1][0][0], Z4, 0, 0, 0); \
        aZ1 = __builtin_amdgcn_mfma_f32_16x16x32_f16(Af, Bf[1][1][0], Z4, 0, 0, 0); \
        aN1 = __builtin_amdgcn_mfma_f32_16x16x32_f16(Af, Bf[1][2][0], Z4, 0, 0, 0); \
        if ((DOHEAD) && w == 0) {                                              \
            f16x8 Bh = *(const f16x8*)(headB + lane * 8);                      \
            aH = __builtin_amdgcn_mfma_f32_16x16x32_f16(Af, Bh, Z4, 0, 0, 0);  \
        }                                                                      \
    }                                                                          \
    _Pragma("unroll")                                                          \
    for (int kt = 1; kt < 8; ++kt) {                                           \
        f16x8 Af = *(const f16x8*)(ab_ + kt * 32);                             \
        aR0 = __builtin_amdgcn_mfma_f32_16x16x32_f16(Af, Bf[0][0][kt], aR0, 0, 0, 0); \
        aZ0 = __builtin_amdgcn_mfma_f32_16x16x32_f16(Af, Bf[0][1][kt], aZ0, 0, 0, 0); \
        aN0 = __builtin_amdgcn_mfma_f32_16x16x32_f16(Af, Bf[0][2][kt], aN0, 0, 0, 0); \
        aR1 = __builtin_amdgcn_mfma_f32_16x16x32_f16(Af, Bf[1][0][kt], aR1, 0, 0, 0); \
        aZ1 = __builtin_amdgcn_mfma_f32_16x16x32_f16(Af, Bf[1][1][kt], aZ1, 0, 0, 0); \
        aN1 = __builtin_amdgcn_mfma_f32_16x16x32_f16(Af, Bf[1][2][kt], aN1, 0, 0, 0); \
        if ((DOHEAD) && w == 0) {                                              \
            f16x8 Bh = *(const f16x8*)(headB + kt * 512 + lane * 8);           \
            aH = __builtin_amdgcn_mfma_f32_16x16x32_f16(Af, Bh, aH, 0, 0, 0);  \
        }                                                                      \
    }                                                                          \
    if ((DOHEAD) && w == 0 && l15 < 2) {                                       \
        const int o = i_ - 1;                                                  \
        _Pragma("unroll")                                                      \
        for (int j = 0; j < 4; ++j)                                            \
            outbuf[(o >> 4) & 1][l15][q * 4 + j][o & 15] = aH[j];              \
    }                                                                          \
    /* gates: batched per-p stages, exp2-prescaled */                          \
    {                                                                          \
        float xr[4];                                                           \
        _Pragma("unroll")                                                      \
        for (int j = 0; j < 4; ++j) xr[j] = xs4[(q * NSTEP + i_) * 4 + j];     \
        float h0n[4], hoy[4];                                                  \
        {   /* p = 0 (even unit) */                                            \
            const f32x4 g0 = *(const f32x4*)(gateC + u0 * GSTR);               \
            const f32x4 g1 = *(const f32x4*)(gateC + u0 * GSTR + 4);           \
            float sr[4], sz[4], pn[4], ab[4], rr[4], zz[4], nn[4];             \
            _Pragma("unroll")                                                  \
            for (int j = 0; j < 4; ++j) {                                      \
                sr[j] = fmaf(xr[j], g0[0], g0[3]) + aR0[j];                    \
                sz[j] = fmaf(xr[j], g0[1], g1[0]) + aZ0[j];                    \
                pn[j] = fmaf(xr[j], g0[2], g1[1]);                             \
                ab[j] = aN0[j] + g1[2];                                        \
            }                                                                  \
            _Pragma("unroll")                                                  \
            for (int j = 0; j < 4; ++j)                                        \
                rr[j] = __builtin_amdgcn_rcpf(1.f + EXP2(sr[j]));              \
            _Pragma("unroll")                                                  \
            for (int j = 0; j < 4; ++j)                                        \
                zz[j] = __builtin_amdgcn_rcpf(1.f + EXP2(sz[j]));              \
            _Pragma("unroll")                                                  \
            for (int j = 0; j < 4; ++j) {                                      \
                float sn = fmaf(rr[j], ab[j], pn[j]);                          \
                nn[j] = fmaf(-2.f, __builtin_amdgcn_rcpf(1.f + EXP2(sn)), 1.f);\
            }                                                                  \
            _Pragma("unroll")                                                  \
            for (int j = 0; j < 4; ++j) {                                      \
                const int m = q * 4 + j;                                       \
                float2 ho = *(float2*)(hF + m * FSTR + u0);                    \
                h0n[j] = nn[j] + zz[j] * (ho.x - nn[j]);                       \
                hoy[j] = ho.y;                                                 \
            }                                                                  \
        }                                                                      \
        {   /* p = 1 (odd unit) */                                             \
            const f32x4 g0 = *(const f32x4*)(gateC + u1 * GSTR);               \
            const f32x4 g1 = *(const f32x4*)(gateC + u1 * GSTR + 4);           \
            float sr[4], sz[4], pn[4], ab[4], rr[4], zz[4], nn[4];             \
            _Pragma("unroll")                                                  \
            for (int j = 0; j < 4; ++j) {                                      \
                sr[j] = fmaf(xr[j], g0[0], g0[3]) + aR1[j];                    \
                sz[j] = fmaf(xr[j], g0[1], g1[0]) + aZ1[j];                    \
                pn[j] = fmaf(xr[j], g0[2], g1[1]);                             \
                ab[j] = aN1[j] + g1[2];                                        \
            }                                                                  \
            _Pragma("unroll")                                                  \
            for (int j = 0; j < 4; ++j)                                        \
                rr[j] = __builtin_amdgcn_rcpf(1.f + EXP2(sr[j]));              \
            _Pragma("unroll")                                                  \
            for (int j = 0; j < 4; ++j)                                        \
                zz[j] = __builtin_amdgcn_rcpf(1.f + EXP2(sz[j]));              \
            _Pragma("unroll")                                                  \
            for (int j = 0; j < 4; ++j) {                                      \
                float sn = fmaf(rr[j], ab[j], pn[j]);                          \
                nn[j] = fmaf(-2.f, __builtin_amdgcn_rcpf(1.f + EXP2(sn)), 1.f);\
            }                                                                  \
            _Pragma("unroll")                                                  \
            for (int j = 0; j < 4; ++j) {                                      \
                const int m = q * 4 + j;                                       \
                float h1n = nn[j] + zz[j] * (hoy[j] - nn[j]);                  \
                *(float2*)(hF + m * FSTR + u0) = (float2){h0n[j], h1n};        \
                *(f16x2*)((HN) + m * HSTR + u0) =                              \
                    (f16x2){(_Float16)h0n[j], (_Float16)h1n};                  \
            }                                                                  \
        }                                                                      \
    }                                                                          \
    __syncthreads();                                                           \
} while (0)

    // step 0 (no head), then pairs (1,2)..(255,256): h_i in hA for even i
    GRU_STEP(hA, hB, 0, false);
    for (int i = 1; i < 256; i += 2) {
        GRU_STEP(hB, hA, i, true);
        GRU_STEP(hA, hB, i + 1, true);
    }

    // epilogue: head-only for o = 256 (reads h_257 in hB)
    {
        if (w == 0) {
            f32x4 aH = Z4;
            const _Float16* ab_ = hB + l15 * HSTR + q * 8;
            #pragma unroll
            for (int kt = 0; kt < 8; ++kt) {
                f16x8 Af = *(const f16x8*)(ab_ + kt * 32);
                f16x8 Bh = *(const f16x8*)(headB + kt * 512 + lane * 8);
                aH = __builtin_amdgcn_mfma_f32_16x16x32_f16(Af, Bh, aH, 0, 0, 0);
            }
            if (l15 < 2) {
                #pragma unroll
                for (int j = 0; j < 4; ++j)
                    outbuf[0][l15][q * 4 + j][0] = aH[j];   // o=256: parity 0, slot 0
            }
        }
        __syncthreads();
        // final flushes: chunk 240 (parity 1, full) + output 256 (parity 0)
        const int e     = tid & 15;
        const int row   = (tid >> 4) & 15;
        const int plane = tid >> 8;
        out[(size_t)plane * ((size_t)Bc * NSTEP)
            + (size_t)(row0 + row) * NSTEP + 240 + e]
            = outbuf[1][plane][row][e] + bh2[plane];
        if (e == 0)
            out[(size_t)plane * ((size_t)Bc * NSTEP)
                + (size_t)(row0 + row) * NSTEP + 256]
                = outbuf[0][plane][row][0] + bh2[plane];
    }
#undef GRU_STEP
}

// ---------------------------------------------------------------------------
extern "C" void kernel_launch(void* const* d_in, const int* in_sizes, int n_in,
                              void* d_out, int out_size, void* d_ws, size_t ws_size,
                              hipStream_t stream) {
    const float* cond   = (const float*)d_in[0];
    const float* ivf    = (const float*)d_in[1];
    const float* times  = (const float*)d_in[2];
    // d_in[3] = seq_lens (unused by reference)
    const float* w1     = (const float*)d_in[4];
    const float* b1     = (const float*)d_in[5];
    const float* w2     = (const float*)d_in[6];
    const float* b2     = (const float*)d_in[7];
    const float* w3     = (const float*)d_in[8];
    const float* b3     = (const float*)d_in[9];
    const float* wh0    = (const float*)d_in[10];
    const float* bh0    = (const float*)d_in[11];
    const float* w_ih   = (const float*)d_in[12];
    const float* b_ih   = (const float*)d_in[13];
    const float* w_hh   = (const float*)d_in[14];
    const float* b_hh   = (const float*)d_in[15];
    const float* w_head = (const float*)d_in[16];
    const float* b_head = (const float*)d_in[17];

    float*    outp = (float*)d_out;
    _Float16* ws   = (_Float16*)d_ws;

    build_frags<<<98, 256, 0, stream>>>(w_hh, w_head, ws);
    gru_mfma<<<Bc / RB, 512, 0, stream>>>(cond, ivf, times,
                                          w1, b1, w2, b2, w3, b3, wh0, bh0,
                                          w_ih, b_ih, b_hh, b_head,
                                          (const _Float16*)ws, outp);
}